// Round 16
// baseline (77.067 us; speedup 1.0000x reference)
//
#include <hip/hip_runtime.h>
#include <hip/hip_bf16.h>

typedef unsigned short u16;
typedef __bf16 bf16x8 __attribute__((ext_vector_type(8)));
typedef float f32x4 __attribute__((ext_vector_type(4)));

// ---- manual fp32 -> bf16 (round-to-nearest-even) ----
__device__ __forceinline__ u16 f2bf(float f) {
    unsigned u = __float_as_uint(f);
    u = u + 0x7fffu + ((u >> 16) & 1u);   // RNE
    return (u16)(u >> 16);
}

// =====================================================================================
// K0: fp32 -> bf16 convert (W only, 64Ki elements — tiny)
// =====================================================================================
__global__ __launch_bounds__(256) void k_convert(const float* __restrict__ src,
                                                 u16* __restrict__ dst, int n4) {
    int i = blockIdx.x * blockDim.x + threadIdx.x;
    if (i >= n4) return;
    float4 v = reinterpret_cast<const float4*>(src)[i];
    ushort4 o;
    o.x = f2bf(v.x); o.y = f2bf(v.y); o.z = f2bf(v.z); o.w = f2bf(v.w);
    reinterpret_cast<ushort4*>(dst)[i] = o;
}

// =====================================================================================
// K1: Y = emb @ W^T, int8 quantized with PER-32-ROW-BLOCK scale, PERMUTED layout:
//   physical byte p(d) = ((d&63)>>2)*16 + (d>>6)*4 + (d&3)
// BM=32 tile (was 64): 1563 blocks -> ~6 resident blocks/CU (was 3) for block-level
// staging/compute overlap; 8 staging loads/thread (lower VGPR -> deeper MLP).
// Same single-barrier sync topology as the R11-proven structure.
// =====================================================================================
__global__ __launch_bounds__(256) void k_emb_gemm_q8(
        const float* __restrict__ emb,       // [n][256] fp32
        const u16* __restrict__ wbf,         // [256][256] bf16 (row = out_dim, col = k)
        signed char* __restrict__ Y8,        // [m_pad][256] int8 (permuted rows)
        float* __restrict__ scaleB,          // [m_pad/32] fp32 (blockmax/127)
        int n_nodes) {
    __shared__ u16 As[32][264];              // 16,896 B (row pad breaks bank stride)
    __shared__ float smax[4];
    __shared__ float sinv_s;                 // 127 / blockmax
    int tid  = threadIdx.x;
    int lane = tid & 63;
    int w    = tid >> 6;
    int r0   = blockIdx.x * 32;
    int c0   = w * 64;
    int l15  = lane & 15;
    int lg   = lane >> 4;                    // k-subblock / row-subblock selector

    // ---- stage A (32 x 256 fp32 -> bf16 LDS), perfectly coalesced ----
    {
        const float4* E4 = reinterpret_cast<const float4*>(emb);
        int c16 = tid & 63;                  // float4 column 0..63
        int rsub = tid >> 6;                 // 0..3
        #pragma unroll
        for (int i = 0; i < 8; ++i) {
            int row = i * 4 + rsub;
            int gr  = r0 + row;
            if (gr >= n_nodes) gr = n_nodes - 1;   // clamp; pad rows harmless
            float4 v = E4[(size_t)gr * 64 + c16];
            ushort4 o;
            o.x = f2bf(v.x); o.y = f2bf(v.y); o.z = f2bf(v.z); o.w = f2bf(v.w);
            *reinterpret_cast<ushort4*>(&As[row][c16 * 4]) = o;
        }
    }
    __syncthreads();

    const bf16x8* B8 = reinterpret_cast<const bf16x8*>(wbf);

    f32x4 acc[2][4];
    #pragma unroll
    for (int mt = 0; mt < 2; ++mt)
        #pragma unroll
        for (int nt = 0; nt < 4; ++nt)
            acc[mt][nt] = (f32x4){0.f, 0.f, 0.f, 0.f};

    #pragma unroll
    for (int kt = 0; kt < 8; ++kt) {         // K = 256 = 8*32
        bf16x8 a[2], b[4];
        #pragma unroll
        for (int mt = 0; mt < 2; ++mt)
            a[mt] = *reinterpret_cast<const bf16x8*>(&As[mt * 16 + l15][kt * 32 + lg * 8]);
        #pragma unroll
        for (int nt = 0; nt < 4; ++nt)
            b[nt] = B8[(c0 + nt * 16 + l15) * 32 + kt * 4 + lg];
        #pragma unroll
        for (int mt = 0; mt < 2; ++mt)
            #pragma unroll
            for (int nt = 0; nt < 4; ++nt)
                acc[mt][nt] = __builtin_amdgcn_mfma_f32_16x16x32_bf16(
                                  a[mt], b[nt], acc[mt][nt], 0, 0, 0);
    }

    // ---- epilogue: block absmax -> one scale -> int8 quantize (permuted store) ----
    // C layout: reg j -> row = mt*16 + lg*4 + j, col = c0 + nt*16 + l15
    float wm = 0.f;
    #pragma unroll
    for (int mt = 0; mt < 2; ++mt)
        #pragma unroll
        for (int nt = 0; nt < 4; ++nt)
            #pragma unroll
            for (int j = 0; j < 4; ++j)
                wm = fmaxf(wm, fabsf(acc[mt][nt][j]));
    #pragma unroll
    for (int m = 1; m < 64; m <<= 1)
        wm = fmaxf(wm, __shfl_xor(wm, m, 64));
    if (lane == 0) smax[w] = wm;             // per-wave block-partial max
    __syncthreads();
    if (tid == 0) {
        float m = fmaxf(fmaxf(smax[0], smax[1]), fmaxf(smax[2], smax[3]));
        m = fmaxf(m, 1e-20f);
        sinv_s = 127.0f / m;
        scaleB[blockIdx.x] = m * (1.0f / 127.0f);
    }
    __syncthreads();
    float iv = sinv_s;

    #pragma unroll
    for (int mt = 0; mt < 2; ++mt) {
        #pragma unroll
        for (int j = 0; j < 4; ++j) {
            int rl = mt * 16 + lg * 4 + j;
            size_t rowb = (size_t)(r0 + rl) * 256;
            #pragma unroll
            for (int nt = 0; nt < 4; ++nt) {
                int d = c0 + nt * 16 + l15;                   // logical dim
                int p = ((d & 63) >> 2) * 16 + (d >> 6) * 4 + (d & 3);
                float v = acc[mt][nt][j] * iv;
                int q = (int)rintf(fminf(fmaxf(v, -127.f), 127.f));
                Y8[rowb + p] = (signed char)q;
            }
        }
    }
}

// =====================================================================================
// K2: out = normalize(relu(mean(dequant(Y8[nbrs]), axis=1)))  -- fp32 out (nontemporal)
// 16-lane group per node; lane l reads one uint4 = dims {64k+4l+0..3}.
// 16 row loads back-to-back. Scale lookup = scaleB[row>>5] (6KB table, cache-hot).
// (At structural roofline per R7/R11/R15 ablations: L1 line-request-rate bound.)
// =====================================================================================
__global__ __launch_bounds__(256) void k_gather_norm_i8(
        const int* __restrict__ nbrs,
        const uint4* __restrict__ Y8q,       // row stride = 16 uint4 (256 int8)
        const float* __restrict__ scaleB,    // [m_pad/32]
        float* __restrict__ out, int n_nodes) {
    __shared__ int   snbr[256];
    __shared__ float ssc[256];
    int t = threadIdx.x;
    int nb0 = blockIdx.x * 16;
    {
        int gi = nb0 * 16 + t;               // 16 nodes x 16 nbrs = 256 = blockDim
        int idx = (gi < n_nodes * 16) ? nbrs[gi] : 0;
        snbr[t] = idx;
        ssc[t]  = scaleB[idx >> 5];          // 6KB table -> cache-hot
    }
    __syncthreads();

    int g = t >> 4;                          // node-in-block 0..15
    int l = t & 15;                          // owns dims {64k + 4l + 0..3}
    int node = nb0 + g;
    if (node >= n_nodes) return;

    // issue all 16 row loads back-to-back (16 outstanding per thread)
    uint4 u[16];
    #pragma unroll
    for (int j = 0; j < 16; ++j)
        u[j] = Y8q[(size_t)snbr[g * 16 + j] * 16 + l];

    float s[16];                             // s[4k+b] = dim 64k + 4l + b
    #pragma unroll
    for (int i = 0; i < 16; ++i) s[i] = 0.f;

    #pragma unroll
    for (int j = 0; j < 16; ++j) {
        float c = ssc[g * 16 + j];
        unsigned w0 = u[j].x, w1 = u[j].y, w2 = u[j].z, w3 = u[j].w;
        s[ 0] += c * (float)((int)(w0 << 24) >> 24);
        s[ 1] += c * (float)((int)(w0 << 16) >> 24);
        s[ 2] += c * (float)((int)(w0 <<  8) >> 24);
        s[ 3] += c * (float)((int) w0        >> 24);
        s[ 4] += c * (float)((int)(w1 << 24) >> 24);
        s[ 5] += c * (float)((int)(w1 << 16) >> 24);
        s[ 6] += c * (float)((int)(w1 <<  8) >> 24);
        s[ 7] += c * (float)((int) w1        >> 24);
        s[ 8] += c * (float)((int)(w2 << 24) >> 24);
        s[ 9] += c * (float)((int)(w2 << 16) >> 24);
        s[10] += c * (float)((int)(w2 <<  8) >> 24);
        s[11] += c * (float)((int) w2        >> 24);
        s[12] += c * (float)((int)(w3 << 24) >> 24);
        s[13] += c * (float)((int)(w3 << 16) >> 24);
        s[14] += c * (float)((int)(w3 <<  8) >> 24);
        s[15] += c * (float)((int) w3        >> 24);
    }

    // mean + relu + ssq
    float q = 0.f;
    #pragma unroll
    for (int i = 0; i < 16; ++i) {
        float v = fmaxf(s[i] * 0.0625f, 0.f);
        s[i] = v;
        q += v * v;
    }
    // reduce across the 16 lanes of this group (xor bits 0..3 stay in-group)
    #pragma unroll
    for (int m = 1; m < 16; m <<= 1)
        q += __shfl_xor(q, m, 64);
    float iv = 1.f / fmaxf(sqrtf(q), 1e-12f);

    // store k: dims 64k+4l+0..3 at float offset node*256 + 64k + 4l
    f32x4* ob = reinterpret_cast<f32x4*>(out) + (size_t)node * 64 + l;
    #pragma unroll
    for (int k = 0; k < 4; ++k) {
        f32x4 v = {s[4*k+0] * iv, s[4*k+1] * iv, s[4*k+2] * iv, s[4*k+3] * iv};
        __builtin_nontemporal_store(v, &ob[k * 16]);
    }
}

// =====================================================================================
// Fallback (only if ws too small): fully fused fp32, one block per node
// =====================================================================================
__global__ __launch_bounds__(256) void k_fused_fallback(const int* __restrict__ nbrs,
        const float* __restrict__ emb, const float* __restrict__ W,
        float* __restrict__ out, int n_nodes) {
    __shared__ __align__(16) float h[256];
    __shared__ int sn[16];
    __shared__ float sred[4];
    int i = blockIdx.x;
    int t = threadIdx.x;
    if (t < 16) sn[t] = nbrs[i * 16 + t];
    __syncthreads();
    float s = 0.f;
    #pragma unroll
    for (int j = 0; j < 16; ++j) s += emb[sn[j] * 256 + t];
    h[t] = s * 0.0625f;
    __syncthreads();
    const float4* W4 = reinterpret_cast<const float4*>(W);
    const float4* h4 = reinterpret_cast<const float4*>(h);
    float y = 0.f;
    #pragma unroll 8
    for (int k4 = 0; k4 < 64; ++k4) {
        float4 wv = W4[t * 64 + k4];
        float4 hv = h4[k4];
        y += wv.x * hv.x + wv.y * hv.y + wv.z * hv.z + wv.w * hv.w;
    }
    y = fmaxf(y, 0.f);
    float q = y * y;
    #pragma unroll
    for (int m = 1; m < 64; m <<= 1) q += __shfl_xor(q, m, 64);
    if ((t & 63) == 0) sred[t >> 6] = q;
    __syncthreads();
    float tot = sred[0] + sred[1] + sred[2] + sred[3];
    out[i * 256 + t] = y * (1.f / fmaxf(sqrtf(tot), 1e-12f));
}

extern "C" void kernel_launch(void* const* d_in, const int* in_sizes, int n_in,
                              void* d_out, int out_size, void* d_ws, size_t ws_size,
                              hipStream_t stream) {
    const int*   nbrs = (const int*)d_in[0];     // [n_nodes, 16]
    const float* emb  = (const float*)d_in[1];   // [n_nodes, 256] fp32
    const float* W    = (const float*)d_in[2];   // [256, 256] fp32 (out, in)
    float* out = (float*)d_out;

    const int degree = 16, dim = 256;
    const int n_nodes = in_sizes[0] / degree;            // 50000
    const int m_pad   = (n_nodes + 31) & ~31;            // 50016
    const int nblks   = m_pad / 32;                      // 1563

    // ws layout: bf16 W (128 KiB) + int8 Y (m_pad*256 B) + fp32 scaleB (nblks*4 B)
    size_t off_w  = 0;
    size_t sz_w   = (size_t)dim * dim * 2;
    size_t off_y  = (off_w + sz_w + 255) & ~(size_t)255;
    size_t sz_y   = (size_t)m_pad * dim;
    size_t off_sc = (off_y + sz_y + 255) & ~(size_t)255;
    size_t sz_sc  = (size_t)nblks * 4;
    size_t need   = off_sc + sz_sc;

    if (ws_size < need) {
        k_fused_fallback<<<n_nodes, 256, 0, stream>>>(nbrs, emb, W, out, n_nodes);
        return;
    }

    char* ws = (char*)d_ws;
    u16*         w_bf = (u16*)(ws + off_w);
    signed char* y8   = (signed char*)(ws + off_y);
    float*       scB  = (float*)(ws + off_sc);

    int n4w = dim * dim / 4;                              // 16384
    k_convert<<<(n4w + 255) / 256, 256, 0, stream>>>(W, w_bf, n4w);

    k_emb_gemm_q8<<<nblks, 256, 0, stream>>>(emb, w_bf, y8, scB, n_nodes);

    int gblk = (n_nodes + 15) / 16;                       // 3125
    k_gather_norm_i8<<<gblk, 256, 0, stream>>>(nbrs, (const uint4*)y8, scB, out, n_nodes);
}

// Round 17
// 66.856 us; speedup vs baseline: 1.1527x; 1.1527x over previous
//
#include <hip/hip_runtime.h>
#include <hip/hip_bf16.h>

typedef unsigned short u16;
typedef __bf16 bf16x8 __attribute__((ext_vector_type(8)));
typedef float f32x4 __attribute__((ext_vector_type(4)));

// ---- manual fp32 -> bf16 (round-to-nearest-even) ----
__device__ __forceinline__ u16 f2bf(float f) {
    unsigned u = __float_as_uint(f);
    u = u + 0x7fffu + ((u >> 16) & 1u);   // RNE
    return (u16)(u >> 16);
}

// =====================================================================================
// K0: fp32 -> bf16 convert (W only, 64Ki elements — tiny)
// =====================================================================================
__global__ __launch_bounds__(256) void k_convert(const float* __restrict__ src,
                                                 u16* __restrict__ dst, int n4) {
    int i = blockIdx.x * blockDim.x + threadIdx.x;
    if (i >= n4) return;
    float4 v = reinterpret_cast<const float4*>(src)[i];
    ushort4 o;
    o.x = f2bf(v.x); o.y = f2bf(v.y); o.z = f2bf(v.z); o.w = f2bf(v.w);
    reinterpret_cast<ushort4*>(dst)[i] = o;
}

// =====================================================================================
// K1: Y = emb @ W^T, int8 quantized (per-64-row-block scale), PERMUTED row layout:
//   physical byte p(d) = ((d&63)>>2)*16 + (d>>6)*4 + (d&3)
// R15-proven structure (BM=64, reg->LDS staging, single-shot). NEW epilogue:
// quantize into an LDS byte scratch (reusing the dead A-tile buffer), then 4
// fully-coalesced dwordx4 stores/thread — replaces 64 scattered byte-stores/thread
// (16x fewer VMEM store requests; same bytes, same numerics).
// =====================================================================================
__global__ __launch_bounds__(256) void k_emb_gemm_q8(
        const float* __restrict__ emb,       // [n][256] fp32
        const u16* __restrict__ wbf,         // [256][256] bf16 (row = out_dim, col = k)
        signed char* __restrict__ Y8,        // [m_pad][256] int8 (permuted rows)
        float* __restrict__ scaleB,          // [m_pad/64] fp32 (blockmax/127)
        int n_nodes) {
    __shared__ u16 As[64][264];              // 33,792 B; reused as byte scratch later
    __shared__ float smax[4];
    __shared__ float sinv_s;                 // 127 / blockmax
    int tid  = threadIdx.x;
    int lane = tid & 63;
    int w    = tid >> 6;
    int r0   = blockIdx.x * 64;
    int c0   = w * 64;
    int l15  = lane & 15;
    int lg   = lane >> 4;                    // k-subblock / row-subblock selector

    // ---- stage A (64 x 256 fp32 -> bf16 LDS), perfectly coalesced ----
    {
        const float4* E4 = reinterpret_cast<const float4*>(emb);
        int c16 = tid & 63;                  // float4 column 0..63
        int rsub = tid >> 6;                 // 0..3
        #pragma unroll
        for (int i = 0; i < 16; ++i) {
            int row = i * 4 + rsub;
            int gr  = r0 + row;
            if (gr >= n_nodes) gr = n_nodes - 1;   // clamp; pad rows harmless
            float4 v = E4[(size_t)gr * 64 + c16];
            ushort4 o;
            o.x = f2bf(v.x); o.y = f2bf(v.y); o.z = f2bf(v.z); o.w = f2bf(v.w);
            *reinterpret_cast<ushort4*>(&As[row][c16 * 4]) = o;
        }
    }
    __syncthreads();

    const bf16x8* B8 = reinterpret_cast<const bf16x8*>(wbf);

    f32x4 acc[4][4];
    #pragma unroll
    for (int mt = 0; mt < 4; ++mt)
        #pragma unroll
        for (int nt = 0; nt < 4; ++nt)
            acc[mt][nt] = (f32x4){0.f, 0.f, 0.f, 0.f};

    #pragma unroll
    for (int kt = 0; kt < 8; ++kt) {         // K = 256 = 8*32
        bf16x8 a[4], b[4];
        #pragma unroll
        for (int mt = 0; mt < 4; ++mt)
            a[mt] = *reinterpret_cast<const bf16x8*>(&As[mt * 16 + l15][kt * 32 + lg * 8]);
        #pragma unroll
        for (int nt = 0; nt < 4; ++nt)
            b[nt] = B8[(c0 + nt * 16 + l15) * 32 + kt * 4 + lg];
        #pragma unroll
        for (int mt = 0; mt < 4; ++mt)
            #pragma unroll
            for (int nt = 0; nt < 4; ++nt)
                acc[mt][nt] = __builtin_amdgcn_mfma_f32_16x16x32_bf16(
                                  a[mt], b[nt], acc[mt][nt], 0, 0, 0);
    }

    // ---- epilogue: block absmax -> one scale ----
    float wm = 0.f;
    #pragma unroll
    for (int mt = 0; mt < 4; ++mt)
        #pragma unroll
        for (int nt = 0; nt < 4; ++nt)
            #pragma unroll
            for (int j = 0; j < 4; ++j)
                wm = fmaxf(wm, fabsf(acc[mt][nt][j]));
    #pragma unroll
    for (int m = 1; m < 64; m <<= 1)
        wm = fmaxf(wm, __shfl_xor(wm, m, 64));
    if (lane == 0) smax[w] = wm;             // per-wave block-partial max
    __syncthreads();                          // (also orders all As reads before reuse)
    if (tid == 0) {
        float m = fmaxf(fmaxf(smax[0], smax[1]), fmaxf(smax[2], smax[3]));
        m = fmaxf(m, 1e-20f);
        sinv_s = 127.0f / m;
        scaleB[blockIdx.x] = m * (1.0f / 127.0f);
    }
    __syncthreads();
    float iv = sinv_s;

    // ---- quantize into LDS byte scratch [64 rows][256 bytes], permuted p(d) ----
    signed char* sc8 = reinterpret_cast<signed char*>(&As[0][0]);   // 16,384 B used
    #pragma unroll
    for (int mt = 0; mt < 4; ++mt) {
        #pragma unroll
        for (int j = 0; j < 4; ++j) {
            int rl = mt * 16 + lg * 4 + j;
            #pragma unroll
            for (int nt = 0; nt < 4; ++nt) {
                int d = c0 + nt * 16 + l15;                   // logical dim
                int p = ((d & 63) >> 2) * 16 + (d >> 6) * 4 + (d & 3);
                float v = acc[mt][nt][j] * iv;
                int q = (int)rintf(fminf(fmaxf(v, -127.f), 127.f));
                sc8[rl * 256 + p] = (signed char)q;
            }
        }
    }
    __syncthreads();

    // ---- coalesced writeback: 4 x dwordx4 per thread (1 KB/instr across the wave) ----
    {
        const uint4* sv = reinterpret_cast<const uint4*>(sc8);       // 1024 uint4
        uint4* Yv = reinterpret_cast<uint4*>(Y8 + (size_t)r0 * 256);
        #pragma unroll
        for (int k = 0; k < 4; ++k) {
            int idx = k * 256 + tid;
            Yv[idx] = sv[idx];
        }
    }
}

// =====================================================================================
// K2: out = normalize(relu(mean(dequant(Y8[nbrs]), axis=1)))  -- fp32 out (nontemporal)
// 16-lane group per node; lane l reads one uint4 = dims {64k+4l+0..3}.
// 16 row loads back-to-back. Scale lookup = scaleB[row>>6] (3KB table, cache-hot).
// (At structural roofline per R7/R11/R15 ablations: random-granule request-rate bound.)
// =====================================================================================
__global__ __launch_bounds__(256) void k_gather_norm_i8(
        const int* __restrict__ nbrs,
        const uint4* __restrict__ Y8q,       // row stride = 16 uint4 (256 int8)
        const float* __restrict__ scaleB,    // [m_pad/64]
        float* __restrict__ out, int n_nodes) {
    __shared__ int   snbr[256];
    __shared__ float ssc[256];
    int t = threadIdx.x;
    int nb0 = blockIdx.x * 16;
    {
        int gi = nb0 * 16 + t;               // 16 nodes x 16 nbrs = 256 = blockDim
        int idx = (gi < n_nodes * 16) ? nbrs[gi] : 0;
        snbr[t] = idx;
        ssc[t]  = scaleB[idx >> 6];          // 3KB table -> cache-hot
    }
    __syncthreads();

    int g = t >> 4;                          // node-in-block 0..15
    int l = t & 15;                          // owns dims {64k + 4l + 0..3}
    int node = nb0 + g;
    if (node >= n_nodes) return;

    // issue all 16 row loads back-to-back (16 outstanding per thread)
    uint4 u[16];
    #pragma unroll
    for (int j = 0; j < 16; ++j)
        u[j] = Y8q[(size_t)snbr[g * 16 + j] * 16 + l];

    float s[16];                             // s[4k+b] = dim 64k + 4l + b
    #pragma unroll
    for (int i = 0; i < 16; ++i) s[i] = 0.f;

    #pragma unroll
    for (int j = 0; j < 16; ++j) {
        float c = ssc[g * 16 + j];
        unsigned w0 = u[j].x, w1 = u[j].y, w2 = u[j].z, w3 = u[j].w;
        s[ 0] += c * (float)((int)(w0 << 24) >> 24);
        s[ 1] += c * (float)((int)(w0 << 16) >> 24);
        s[ 2] += c * (float)((int)(w0 <<  8) >> 24);
        s[ 3] += c * (float)((int) w0        >> 24);
        s[ 4] += c * (float)((int)(w1 << 24) >> 24);
        s[ 5] += c * (float)((int)(w1 << 16) >> 24);
        s[ 6] += c * (float)((int)(w1 <<  8) >> 24);
        s[ 7] += c * (float)((int) w1        >> 24);
        s[ 8] += c * (float)((int)(w2 << 24) >> 24);
        s[ 9] += c * (float)((int)(w2 << 16) >> 24);
        s[10] += c * (float)((int)(w2 <<  8) >> 24);
        s[11] += c * (float)((int) w2        >> 24);
        s[12] += c * (float)((int)(w3 << 24) >> 24);
        s[13] += c * (float)((int)(w3 << 16) >> 24);
        s[14] += c * (float)((int)(w3 <<  8) >> 24);
        s[15] += c * (float)((int) w3        >> 24);
    }

    // mean + relu + ssq
    float q = 0.f;
    #pragma unroll
    for (int i = 0; i < 16; ++i) {
        float v = fmaxf(s[i] * 0.0625f, 0.f);
        s[i] = v;
        q += v * v;
    }
    // reduce across the 16 lanes of this group (xor bits 0..3 stay in-group)
    #pragma unroll
    for (int m = 1; m < 16; m <<= 1)
        q += __shfl_xor(q, m, 64);
    float iv = 1.f / fmaxf(sqrtf(q), 1e-12f);

    // store k: dims 64k+4l+0..3 at float offset node*256 + 64k + 4l
    f32x4* ob = reinterpret_cast<f32x4*>(out) + (size_t)node * 64 + l;
    #pragma unroll
    for (int k = 0; k < 4; ++k) {
        f32x4 v = {s[4*k+0] * iv, s[4*k+1] * iv, s[4*k+2] * iv, s[4*k+3] * iv};
        __builtin_nontemporal_store(v, &ob[k * 16]);
    }
}

// =====================================================================================
// Fallback (only if ws too small): fully fused fp32, one block per node
// =====================================================================================
__global__ __launch_bounds__(256) void k_fused_fallback(const int* __restrict__ nbrs,
        const float* __restrict__ emb, const float* __restrict__ W,
        float* __restrict__ out, int n_nodes) {
    __shared__ __align__(16) float h[256];
    __shared__ int sn[16];
    __shared__ float sred[4];
    int i = blockIdx.x;
    int t = threadIdx.x;
    if (t < 16) sn[t] = nbrs[i * 16 + t];
    __syncthreads();
    float s = 0.f;
    #pragma unroll
    for (int j = 0; j < 16; ++j) s += emb[sn[j] * 256 + t];
    h[t] = s * 0.0625f;
    __syncthreads();
    const float4* W4 = reinterpret_cast<const float4*>(W);
    const float4* h4 = reinterpret_cast<const float4*>(h);
    float y = 0.f;
    #pragma unroll 8
    for (int k4 = 0; k4 < 64; ++k4) {
        float4 wv = W4[t * 64 + k4];
        float4 hv = h4[k4];
        y += wv.x * hv.x + wv.y * hv.y + wv.z * hv.z + wv.w * hv.w;
    }
    y = fmaxf(y, 0.f);
    float q = y * y;
    #pragma unroll
    for (int m = 1; m < 64; m <<= 1) q += __shfl_xor(q, m, 64);
    if ((t & 63) == 0) sred[t >> 6] = q;
    __syncthreads();
    float tot = sred[0] + sred[1] + sred[2] + sred[3];
    out[i * 256 + t] = y * (1.f / fmaxf(sqrtf(tot), 1e-12f));
}

extern "C" void kernel_launch(void* const* d_in, const int* in_sizes, int n_in,
                              void* d_out, int out_size, void* d_ws, size_t ws_size,
                              hipStream_t stream) {
    const int*   nbrs = (const int*)d_in[0];     // [n_nodes, 16]
    const float* emb  = (const float*)d_in[1];   // [n_nodes, 256] fp32
    const float* W    = (const float*)d_in[2];   // [256, 256] fp32 (out, in)
    float* out = (float*)d_out;

    const int degree = 16, dim = 256;
    const int n_nodes = in_sizes[0] / degree;            // 50000
    const int m_pad   = (n_nodes + 63) & ~63;            // 50048
    const int nblks   = m_pad / 64;                      // 782

    // ws layout: bf16 W (128 KiB) + int8 Y (m_pad*256 B) + fp32 scaleB (nblks*4 B)
    size_t off_w  = 0;
    size_t sz_w   = (size_t)dim * dim * 2;
    size_t off_y  = (off_w + sz_w + 255) & ~(size_t)255;
    size_t sz_y   = (size_t)m_pad * dim;
    size_t off_sc = (off_y + sz_y + 255) & ~(size_t)255;
    size_t sz_sc  = (size_t)nblks * 4;
    size_t need   = off_sc + sz_sc;

    if (ws_size < need) {
        k_fused_fallback<<<n_nodes, 256, 0, stream>>>(nbrs, emb, W, out, n_nodes);
        return;
    }

    char* ws = (char*)d_ws;
    u16*         w_bf = (u16*)(ws + off_w);
    signed char* y8   = (signed char*)(ws + off_y);
    float*       scB  = (float*)(ws + off_sc);

    int n4w = dim * dim / 4;                              // 16384
    k_convert<<<(n4w + 255) / 256, 256, 0, stream>>>(W, w_bf, n4w);

    k_emb_gemm_q8<<<nblks, 256, 0, stream>>>(emb, w_bf, y8, scB, n_nodes);

    int gblk = (n_nodes + 15) / 16;                       // 3125
    k_gather_norm_i8<<<gblk, 256, 0, stream>>>(nbrs, (const uint4*)y8, scB, out, n_nodes);
}

// Round 18
// 66.582 us; speedup vs baseline: 1.1575x; 1.0041x over previous
//
#include <hip/hip_runtime.h>
#include <hip/hip_bf16.h>

typedef unsigned short u16;
typedef __bf16 bf16x8 __attribute__((ext_vector_type(8)));
typedef float f32x4 __attribute__((ext_vector_type(4)));

// ---- manual fp32 -> bf16 (round-to-nearest-even) ----
__device__ __forceinline__ u16 f2bf(float f) {
    unsigned u = __float_as_uint(f);
    u = u + 0x7fffu + ((u >> 16) & 1u);   // RNE
    return (u16)(u >> 16);
}

// =====================================================================================
// K0: fp32 -> bf16 convert (W only, 64Ki elements — tiny)
// =====================================================================================
__global__ __launch_bounds__(256) void k_convert(const float* __restrict__ src,
                                                 u16* __restrict__ dst, int n4) {
    int i = blockIdx.x * blockDim.x + threadIdx.x;
    if (i >= n4) return;
    float4 v = reinterpret_cast<const float4*>(src)[i];
    ushort4 o;
    o.x = f2bf(v.x); o.y = f2bf(v.y); o.z = f2bf(v.z); o.w = f2bf(v.w);
    reinterpret_cast<ushort4*>(dst)[i] = o;
}

// =====================================================================================
// K1: Y = emb @ W^T, int8 quantized (per-64-row-block scale), PERMUTED row layout:
//   physical byte p(d) = ((d&63)>>2)*16 + (d>>6)*4 + (d&3)
// R17 structure + T14 staging split: ALL 16 global loads issued back-to-back into
// registers (one HBM-latency exposure), then convert+ds_write. No sync-topology
// change. Epilogue: quantize to LDS scratch -> 4 coalesced dwordx4 stores/thread.
// =====================================================================================
__global__ __launch_bounds__(256) void k_emb_gemm_q8(
        const float* __restrict__ emb,       // [n][256] fp32
        const u16* __restrict__ wbf,         // [256][256] bf16 (row = out_dim, col = k)
        signed char* __restrict__ Y8,        // [m_pad][256] int8 (permuted rows)
        float* __restrict__ scaleB,          // [m_pad/64] fp32 (blockmax/127)
        int n_nodes) {
    __shared__ u16 As[64][264];              // 33,792 B; reused as byte scratch later
    __shared__ float smax[4];
    __shared__ float sinv_s;                 // 127 / blockmax
    int tid  = threadIdx.x;
    int lane = tid & 63;
    int w    = tid >> 6;
    int r0   = blockIdx.x * 64;
    int c0   = w * 64;
    int l15  = lane & 15;
    int lg   = lane >> 4;                    // k-subblock / row-subblock selector

    // ---- stage A: phase 1 = issue ALL 16 coalesced loads (deep MLP) ----
    {
        const float4* E4 = reinterpret_cast<const float4*>(emb);
        int c16 = tid & 63;                  // float4 column 0..63
        int rsub = tid >> 6;                 // 0..3
        float4 rv[16];
        #pragma unroll
        for (int i = 0; i < 16; ++i) {
            int gr = r0 + i * 4 + rsub;
            if (gr >= n_nodes) gr = n_nodes - 1;   // clamp; pad rows harmless
            rv[i] = E4[(size_t)gr * 64 + c16];
        }
        // ---- phase 2: convert + LDS write ----
        #pragma unroll
        for (int i = 0; i < 16; ++i) {
            ushort4 o;
            o.x = f2bf(rv[i].x); o.y = f2bf(rv[i].y);
            o.z = f2bf(rv[i].z); o.w = f2bf(rv[i].w);
            *reinterpret_cast<ushort4*>(&As[i * 4 + rsub][c16 * 4]) = o;
        }
    }
    __syncthreads();

    const bf16x8* B8 = reinterpret_cast<const bf16x8*>(wbf);

    f32x4 acc[4][4];
    #pragma unroll
    for (int mt = 0; mt < 4; ++mt)
        #pragma unroll
        for (int nt = 0; nt < 4; ++nt)
            acc[mt][nt] = (f32x4){0.f, 0.f, 0.f, 0.f};

    #pragma unroll
    for (int kt = 0; kt < 8; ++kt) {         // K = 256 = 8*32
        bf16x8 a[4], b[4];
        #pragma unroll
        for (int mt = 0; mt < 4; ++mt)
            a[mt] = *reinterpret_cast<const bf16x8*>(&As[mt * 16 + l15][kt * 32 + lg * 8]);
        #pragma unroll
        for (int nt = 0; nt < 4; ++nt)
            b[nt] = B8[(c0 + nt * 16 + l15) * 32 + kt * 4 + lg];
        #pragma unroll
        for (int mt = 0; mt < 4; ++mt)
            #pragma unroll
            for (int nt = 0; nt < 4; ++nt)
                acc[mt][nt] = __builtin_amdgcn_mfma_f32_16x16x32_bf16(
                                  a[mt], b[nt], acc[mt][nt], 0, 0, 0);
    }

    // ---- epilogue: block absmax -> one scale ----
    float wm = 0.f;
    #pragma unroll
    for (int mt = 0; mt < 4; ++mt)
        #pragma unroll
        for (int nt = 0; nt < 4; ++nt)
            #pragma unroll
            for (int j = 0; j < 4; ++j)
                wm = fmaxf(wm, fabsf(acc[mt][nt][j]));
    #pragma unroll
    for (int m = 1; m < 64; m <<= 1)
        wm = fmaxf(wm, __shfl_xor(wm, m, 64));
    if (lane == 0) smax[w] = wm;             // per-wave block-partial max
    __syncthreads();                          // (also orders all As reads before reuse)
    if (tid == 0) {
        float m = fmaxf(fmaxf(smax[0], smax[1]), fmaxf(smax[2], smax[3]));
        m = fmaxf(m, 1e-20f);
        sinv_s = 127.0f / m;
        scaleB[blockIdx.x] = m * (1.0f / 127.0f);
    }
    __syncthreads();
    float iv = sinv_s;

    // ---- quantize into LDS byte scratch [64 rows][256 bytes], permuted p(d) ----
    signed char* sc8 = reinterpret_cast<signed char*>(&As[0][0]);   // 16,384 B used
    #pragma unroll
    for (int mt = 0; mt < 4; ++mt) {
        #pragma unroll
        for (int j = 0; j < 4; ++j) {
            int rl = mt * 16 + lg * 4 + j;
            #pragma unroll
            for (int nt = 0; nt < 4; ++nt) {
                int d = c0 + nt * 16 + l15;                   // logical dim
                int p = ((d & 63) >> 2) * 16 + (d >> 6) * 4 + (d & 3);
                float v = acc[mt][nt][j] * iv;
                int q = (int)rintf(fminf(fmaxf(v, -127.f), 127.f));
                sc8[rl * 256 + p] = (signed char)q;
            }
        }
    }
    __syncthreads();

    // ---- coalesced writeback: 4 x dwordx4 per thread (1 KB/instr across the wave) ----
    {
        const uint4* sv = reinterpret_cast<const uint4*>(sc8);       // 1024 uint4
        uint4* Yv = reinterpret_cast<uint4*>(Y8 + (size_t)r0 * 256);
        #pragma unroll
        for (int k = 0; k < 4; ++k) {
            int idx = k * 256 + tid;
            Yv[idx] = sv[idx];
        }
    }
}

// =====================================================================================
// K2: out = normalize(relu(mean(dequant(Y8[nbrs]), axis=1)))  -- fp32 out (nontemporal)
// 16-lane group per node; lane l reads one uint4 = dims {64k+4l+0..3}.
// 16 row loads back-to-back. Scale lookup = scaleB[row>>6] (3KB table, cache-hot).
// (At structural roofline per R7/R11/R15 ablations: random-granule request-rate bound.)
// =====================================================================================
__global__ __launch_bounds__(256) void k_gather_norm_i8(
        const int* __restrict__ nbrs,
        const uint4* __restrict__ Y8q,       // row stride = 16 uint4 (256 int8)
        const float* __restrict__ scaleB,    // [m_pad/64]
        float* __restrict__ out, int n_nodes) {
    __shared__ int   snbr[256];
    __shared__ float ssc[256];
    int t = threadIdx.x;
    int nb0 = blockIdx.x * 16;
    {
        int gi = nb0 * 16 + t;               // 16 nodes x 16 nbrs = 256 = blockDim
        int idx = (gi < n_nodes * 16) ? nbrs[gi] : 0;
        snbr[t] = idx;
        ssc[t]  = scaleB[idx >> 6];          // 3KB table -> cache-hot
    }
    __syncthreads();

    int g = t >> 4;                          // node-in-block 0..15
    int l = t & 15;                          // owns dims {64k + 4l + 0..3}
    int node = nb0 + g;
    if (node >= n_nodes) return;

    // issue all 16 row loads back-to-back (16 outstanding per thread)
    uint4 u[16];
    #pragma unroll
    for (int j = 0; j < 16; ++j)
        u[j] = Y8q[(size_t)snbr[g * 16 + j] * 16 + l];

    float s[16];                             // s[4k+b] = dim 64k + 4l + b
    #pragma unroll
    for (int i = 0; i < 16; ++i) s[i] = 0.f;

    #pragma unroll
    for (int j = 0; j < 16; ++j) {
        float c = ssc[g * 16 + j];
        unsigned w0 = u[j].x, w1 = u[j].y, w2 = u[j].z, w3 = u[j].w;
        s[ 0] += c * (float)((int)(w0 << 24) >> 24);
        s[ 1] += c * (float)((int)(w0 << 16) >> 24);
        s[ 2] += c * (float)((int)(w0 <<  8) >> 24);
        s[ 3] += c * (float)((int) w0        >> 24);
        s[ 4] += c * (float)((int)(w1 << 24) >> 24);
        s[ 5] += c * (float)((int)(w1 << 16) >> 24);
        s[ 6] += c * (float)((int)(w1 <<  8) >> 24);
        s[ 7] += c * (float)((int) w1        >> 24);
        s[ 8] += c * (float)((int)(w2 << 24) >> 24);
        s[ 9] += c * (float)((int)(w2 << 16) >> 24);
        s[10] += c * (float)((int)(w2 <<  8) >> 24);
        s[11] += c * (float)((int) w2        >> 24);
        s[12] += c * (float)((int)(w3 << 24) >> 24);
        s[13] += c * (float)((int)(w3 << 16) >> 24);
        s[14] += c * (float)((int)(w3 <<  8) >> 24);
        s[15] += c * (float)((int) w3        >> 24);
    }

    // mean + relu + ssq
    float q = 0.f;
    #pragma unroll
    for (int i = 0; i < 16; ++i) {
        float v = fmaxf(s[i] * 0.0625f, 0.f);
        s[i] = v;
        q += v * v;
    }
    // reduce across the 16 lanes of this group (xor bits 0..3 stay in-group)
    #pragma unroll
    for (int m = 1; m < 16; m <<= 1)
        q += __shfl_xor(q, m, 64);
    float iv = 1.f / fmaxf(sqrtf(q), 1e-12f);

    // store k: dims 64k+4l+0..3 at float offset node*256 + 64k + 4l
    f32x4* ob = reinterpret_cast<f32x4*>(out) + (size_t)node * 64 + l;
    #pragma unroll
    for (int k = 0; k < 4; ++k) {
        f32x4 v = {s[4*k+0] * iv, s[4*k+1] * iv, s[4*k+2] * iv, s[4*k+3] * iv};
        __builtin_nontemporal_store(v, &ob[k * 16]);
    }
}

// =====================================================================================
// Fallback (only if ws too small): fully fused fp32, one block per node
// =====================================================================================
__global__ __launch_bounds__(256) void k_fused_fallback(const int* __restrict__ nbrs,
        const float* __restrict__ emb, const float* __restrict__ W,
        float* __restrict__ out, int n_nodes) {
    __shared__ __align__(16) float h[256];
    __shared__ int sn[16];
    __shared__ float sred[4];
    int i = blockIdx.x;
    int t = threadIdx.x;
    if (t < 16) sn[t] = nbrs[i * 16 + t];
    __syncthreads();
    float s = 0.f;
    #pragma unroll
    for (int j = 0; j < 16; ++j) s += emb[sn[j] * 256 + t];
    h[t] = s * 0.0625f;
    __syncthreads();
    const float4* W4 = reinterpret_cast<const float4*>(W);
    const float4* h4 = reinterpret_cast<const float4*>(h);
    float y = 0.f;
    #pragma unroll 8
    for (int k4 = 0; k4 < 64; ++k4) {
        float4 wv = W4[t * 64 + k4];
        float4 hv = h4[k4];
        y += wv.x * hv.x + wv.y * hv.y + wv.z * hv.z + wv.w * hv.w;
    }
    y = fmaxf(y, 0.f);
    float q = y * y;
    #pragma unroll
    for (int m = 1; m < 64; m <<= 1) q += __shfl_xor(q, m, 64);
    if ((t & 63) == 0) sred[t >> 6] = q;
    __syncthreads();
    float tot = sred[0] + sred[1] + sred[2] + sred[3];
    out[i * 256 + t] = y * (1.f / fmaxf(sqrtf(tot), 1e-12f));
}

extern "C" void kernel_launch(void* const* d_in, const int* in_sizes, int n_in,
                              void* d_out, int out_size, void* d_ws, size_t ws_size,
                              hipStream_t stream) {
    const int*   nbrs = (const int*)d_in[0];     // [n_nodes, 16]
    const float* emb  = (const float*)d_in[1];   // [n_nodes, 256] fp32
    const float* W    = (const float*)d_in[2];   // [256, 256] fp32 (out, in)
    float* out = (float*)d_out;

    const int degree = 16, dim = 256;
    const int n_nodes = in_sizes[0] / degree;            // 50000
    const int m_pad   = (n_nodes + 63) & ~63;            // 50048
    const int nblks   = m_pad / 64;                      // 782

    // ws layout: bf16 W (128 KiB) + int8 Y (m_pad*256 B) + fp32 scaleB (nblks*4 B)
    size_t off_w  = 0;
    size_t sz_w   = (size_t)dim * dim * 2;
    size_t off_y  = (off_w + sz_w + 255) & ~(size_t)255;
    size_t sz_y   = (size_t)m_pad * dim;
    size_t off_sc = (off_y + sz_y + 255) & ~(size_t)255;
    size_t sz_sc  = (size_t)nblks * 4;
    size_t need   = off_sc + sz_sc;

    if (ws_size < need) {
        k_fused_fallback<<<n_nodes, 256, 0, stream>>>(nbrs, emb, W, out, n_nodes);
        return;
    }

    char* ws = (char*)d_ws;
    u16*         w_bf = (u16*)(ws + off_w);
    signed char* y8   = (signed char*)(ws + off_y);
    float*       scB  = (float*)(ws + off_sc);

    int n4w = dim * dim / 4;                              // 16384
    k_convert<<<(n4w + 255) / 256, 256, 0, stream>>>(W, w_bf, n4w);

    k_emb_gemm_q8<<<nblks, 256, 0, stream>>>(emb, w_bf, y8, scB, n_nodes);

    int gblk = (n_nodes + 15) / 16;                       // 3125
    k_gather_norm_i8<<<gblk, 256, 0, stream>>>(nbrs, (const uint4*)y8, scB, out, n_nodes);
}